// Round 5
// baseline (3071.772 us; speedup 1.0000x reference)
//
#include <hip/hip_runtime.h>
#include <hip/hip_bf16.h>
#include <math.h>

#define B_ 8
#define N_ 8192
#define C_ 64
#define M_ 2048
#define K_ 32
#define OUT_ 128
#define CIN_ 67
#define HID_ 268
#define EPS_ 1e-6f
#define NPROD_ 4       // 4 producer blocks x 2 batches each
#define CONS_ 240      // 8 batches x 30 consumers
#define CAPQ_ 512

typedef short short8 __attribute__((ext_vector_type(8)));
typedef float floatx4 __attribute__((ext_vector_type(4)));

__device__ __forceinline__ unsigned short f2bf(float f) {
  unsigned u = __builtin_bit_cast(unsigned, f);
  u += 0x7fffu + ((u >> 16) & 1u);   // RNE (MFMA input casts only)
  return (unsigned short)(u >> 16);
}
__device__ __forceinline__ float bf2f(unsigned short h) {
  return __builtin_bit_cast(float, (unsigned)h << 16);
}

// Reference-matching distance (verified r13, bit-exact): square fused into the
// 3-element reduce as FMA, index-ascending.
__device__ __forceinline__ float d2fma(float ax, float ay, float az,
                                       float bx, float by, float bz) {
#pragma clang fp contract(off)
  float dx = ax - bx, dy = ay - by, dz = az - bz;
  return __builtin_fmaf(dz, dz, __builtin_fmaf(dy, dy, dx * dx));
}

__device__ __forceinline__ float gelu_tanh(float v) {
  const float k0 = 0.7978845608028654f;  // sqrt(2/pi)
  const float k1 = 0.044715f;
  float u = k0 * (v + k1 * v * v * v);
  return 0.5f * v * (1.0f + tanhf(u));
}

// Morton spread of a 4-bit value to bit positions 0,3,6,9
__device__ __forceinline__ int msp4(int v) {
  return (v & 1) | ((v & 2) << 2) | ((v & 4) << 4) | ((v & 8) << 6);
}

// One DPP max step on a u64 key (VALU-only; keys are unsigned so the
// bound_ctrl zero-fill is the identity for max).
template <int CTRL>
__device__ __forceinline__ unsigned long long dpp_umax64(unsigned long long k) {
  int lo = (int)(unsigned)k;
  int hi = (int)(unsigned)(k >> 32);
  unsigned slo = (unsigned)__builtin_amdgcn_update_dpp(0, lo, CTRL, 0xF, 0xF, true);
  unsigned shi = (unsigned)__builtin_amdgcn_update_dpp(0, hi, CTRL, 0xF, 0xF, true);
  unsigned long long o = ((unsigned long long)shi << 32) | (unsigned long long)slo;
  return k > o ? k : o;
}

__device__ __forceinline__ unsigned long long wave_dpp_max64(unsigned long long kk) {
  kk = dpp_umax64<0x111>(kk);   // row_shr:1
  kk = dpp_umax64<0x112>(kk);   // row_shr:2
  kk = dpp_umax64<0x114>(kk);   // row_shr:4
  kk = dpp_umax64<0x118>(kk);   // row_shr:8
  kk = dpp_umax64<0x142>(kk);   // row_bcast:15
  kk = dpp_umax64<0x143>(kk);   // row_bcast:31
  return kk;                     // lane63 holds the 64-lane max
}

// ---------------- Pack f32 weights into MFMA B-fragment order (bf16) ------
// Also zeroes the (cacheline-padded) progress flags before fused_kernel.
__global__ __launch_bounds__(256) void pack_kernel(
    const float* __restrict__ w1, const float* __restrict__ w2,
    unsigned short* __restrict__ w1p, unsigned short* __restrict__ w2p,
    int* __restrict__ prog) {
  if (blockIdx.x == 0) prog[threadIdx.x] = 0;   // 256 ints = 8 padded lines
  int e = blockIdx.x * 256 + threadIdx.x;
  if (e < 3 * 17 * 64 * 8) {
    int j = e & 7, lane = (e >> 3) & 63, fi = e >> 9;
    int kt = fi / 17, nt = fi - kt * 17;
    int k = kt * 32 + (lane >> 4) * 8 + j;
    int n = nt * 16 + (lane & 15);
    float v = (k < CIN_ && n < HID_) ? w1[k * HID_ + n] : 0.f;
    w1p[e] = f2bf(v);
  } else {
    int e2 = e - 3 * 17 * 64 * 8;
    if (e2 < 9 * 8 * 64 * 8) {
      int j = e2 & 7, lane = (e2 >> 3) & 63, fi = e2 >> 9;
      int kt = fi >> 3, nt = fi & 7;
      int k = kt * 32 + (lane >> 4) * 8 + j;
      int n = nt * 16 + (lane & 15);
      float v = (k < HID_) ? w2[k * OUT_ + n] : 0.f;
      w2p[e2] = f2bf(v);
    }
  }
}

// ---------------- Fused producer (2-batch FPS) + consumer (ballq+MLP) -----
// Blocks 0..3: each runs TWO interleaved FPS chains (batches 2p, 2p+1).
// The two independent serial chains share one barrier per iteration and
// hide each other's DPP/LDS/global latencies. Per-batch math is the
// R2/R4-verified chain, bit-exact (winner coords now read from global x,
// which holds identical bits to the old LDS copy). Centers go through a
// 64-slot LDS ring, flushed + release-published every 32 iterations.
// Blocks 4..243: consumers (m-major pairing, R4-verified math). Spin uses
// RELAXED polls (no L2 invalidation) with an ACQUIRE refresh every 8th
// poll -- fixes the R3/R4 cache-invalidation livelock outlier.
__global__ __launch_bounds__(512) void fused_kernel(
    const float* __restrict__ x, const float* __restrict__ features,
    const int* __restrict__ first_idx,
    const unsigned short* __restrict__ w1p, const float* __restrict__ b1,
    const float* __restrict__ g1, const float* __restrict__ be1,
    const unsigned short* __restrict__ w2p, const float* __restrict__ b2,
    const float* __restrict__ g2, const float* __restrict__ be2,
    float* __restrict__ centers, float* __restrict__ out1,
    int* __restrict__ prog) {
  __shared__ __align__(16) char smem[133632];
  const int tid = threadIdx.x;
  const int lane = tid & 63;
  const int wv = tid >> 6;   // wave 0..7

  if (blockIdx.x < NPROD_) {
    // ======================= FPS producer, 2 batches =======================
    const int bp = blockIdx.x;            // batches 2*bp, 2*bp+1

    float* s_xyz = (float*)smem;                                  // [0,98304)
    int* s_hist = (int*)(smem + 98304);                           // 16 KB
    unsigned short* s_perm = (unsigned short*)(smem + 114688);    // 16 KB
    float* s_ring0 = (float*)(smem + 131072);                     // 64*3 f
    float* s_ring1 = (float*)(smem + 131840);                     // 64*3 f
    unsigned long long* s_went = (unsigned long long*)(smem + 132608); // [2][2][8]
    int* s_wsum = (int*)(smem + 132864);                          // 8
    float* s_bb = (float*)(smem + 132896);                        // [8][6]

    // per-thread state for both batches: slot s = h*16 + i
    float px[32], py[32], pz[32], d[32];
    unsigned lo32[32];
    float gx0[2][2], gx1[2][2], gy0[2][2], gy1[2][2], gz0[2][2], gz1[2][2];
    float ncx[2], ncy[2], ncz[2];

#pragma unroll
    for (int h = 0; h < 2; ++h) {
      const int b = 2 * bp + h;
      const float* xb = x + (size_t)b * N_ * 3;

      // stage coords: 6144 float4, coalesced, 12 per thread
      {
        const float4* src = (const float4*)xb;
        float4* dst = (float4*)s_xyz;
#pragma unroll
        for (int i = 0; i < 12; ++i) {
          int e = tid + i * 512;
          dst[e] = src[e];
        }
      }
      for (int i = tid; i < 4096; i += 512) s_hist[i] = 0;
      __syncthreads();

      // ---- batch bbox (used only for binning) ----
      float bx0 = INFINITY, bx1 = -INFINITY, by0 = INFINITY, by1 = -INFINITY,
            bz0 = INFINITY, bz1 = -INFINITY;
#pragma unroll
      for (int i = 0; i < 16; ++i) {
        int p = tid + i * 512;
        float X = s_xyz[p * 3 + 0], Y = s_xyz[p * 3 + 1], Z = s_xyz[p * 3 + 2];
        bx0 = fminf(bx0, X); bx1 = fmaxf(bx1, X);
        by0 = fminf(by0, Y); by1 = fmaxf(by1, Y);
        bz0 = fminf(bz0, Z); bz1 = fmaxf(bz1, Z);
      }
#pragma unroll
      for (int off = 1; off < 64; off <<= 1) {
        bx0 = fminf(bx0, __shfl_xor(bx0, off)); bx1 = fmaxf(bx1, __shfl_xor(bx1, off));
        by0 = fminf(by0, __shfl_xor(by0, off)); by1 = fmaxf(by1, __shfl_xor(by1, off));
        bz0 = fminf(bz0, __shfl_xor(bz0, off)); bz1 = fmaxf(bz1, __shfl_xor(bz1, off));
      }
      if (lane == 0) {
        s_bb[wv * 6 + 0] = bx0; s_bb[wv * 6 + 1] = bx1; s_bb[wv * 6 + 2] = by0;
        s_bb[wv * 6 + 3] = by1; s_bb[wv * 6 + 4] = bz0; s_bb[wv * 6 + 5] = bz1;
      }
      __syncthreads();
#pragma unroll
      for (int w = 0; w < 8; ++w) {
        bx0 = fminf(bx0, s_bb[w * 6 + 0]); bx1 = fmaxf(bx1, s_bb[w * 6 + 1]);
        by0 = fminf(by0, s_bb[w * 6 + 2]); by1 = fmaxf(by1, s_bb[w * 6 + 3]);
        bz0 = fminf(bz0, s_bb[w * 6 + 4]); bz1 = fmaxf(bz1, s_bb[w * 6 + 5]);
      }
      const float kS = 16.0f * (1.0f - 1e-6f);
      float rx = bx1 - bx0, ry = by1 - by0, rz = bz1 - bz0;
      float sxv = rx > 0.f ? kS / rx : 0.f;
      float syv = ry > 0.f ? kS / ry : 0.f;
      float szv = rz > 0.f ? kS / rz : 0.f;

      // ---- histogram (12-bit Morton cells) ----
#pragma unroll
      for (int i = 0; i < 16; ++i) {
        int p = tid + i * 512;
        int qx = (int)((s_xyz[p * 3 + 0] - bx0) * sxv);
        int qy = (int)((s_xyz[p * 3 + 1] - by0) * syv);
        int qz = (int)((s_xyz[p * 3 + 2] - bz0) * szv);
        qx = qx < 0 ? 0 : (qx > 15 ? 15 : qx);
        qy = qy < 0 ? 0 : (qy > 15 ? 15 : qy);
        qz = qz < 0 ? 0 : (qz > 15 ? 15 : qz);
        int cc = msp4(qx) | (msp4(qy) << 1) | (msp4(qz) << 2);
        atomicAdd(&s_hist[cc], 1);
      }
      __syncthreads();

      // ---- exclusive scan over 4096 bins (thread owns bins [8t,8t+8)) ----
      {
        int hh[8], pre[8];
        int acc = 0;
#pragma unroll
        for (int i = 0; i < 8; ++i) { hh[i] = s_hist[tid * 8 + i]; pre[i] = acc; acc += hh[i]; }
        int incl = acc;
#pragma unroll
        for (int off = 1; off < 64; off <<= 1) {
          int v = __shfl_up(incl, off);
          if (lane >= off) incl += v;
        }
        int texcl = incl - acc;
        if (lane == 63) s_wsum[wv] = incl;
        __syncthreads();
        int woff = 0;
#pragma unroll
        for (int w = 0; w < 8; ++w) woff += (w < wv) ? s_wsum[w] : 0;
#pragma unroll
        for (int i = 0; i < 8; ++i) s_hist[tid * 8 + i] = woff + texcl + pre[i];
      }
      __syncthreads();

      // ---- scatter: s_perm[pos] = original point index ----
#pragma unroll
      for (int i = 0; i < 16; ++i) {
        int p = tid + i * 512;
        int qx = (int)((s_xyz[p * 3 + 0] - bx0) * sxv);
        int qy = (int)((s_xyz[p * 3 + 1] - by0) * syv);
        int qz = (int)((s_xyz[p * 3 + 2] - bz0) * szv);
        qx = qx < 0 ? 0 : (qx > 15 ? 15 : qx);
        qy = qy < 0 ? 0 : (qy > 15 ? 15 : qy);
        qz = qz < 0 ? 0 : (qz > 15 ? 15 : qz);
        int cc = msp4(qx) | (msp4(qy) << 1) | (msp4(qz) << 2);
        int pos = atomicAdd(&s_hist[cc], 1);
        s_perm[pos] = (unsigned short)p;
      }
      __syncthreads();

      // ---- load 16 sorted slots; build 2 group bboxes (8 pts each) ----
#pragma unroll
      for (int g = 0; g < 2; ++g) {
        gx0[h][g] = INFINITY; gx1[h][g] = -INFINITY; gy0[h][g] = INFINITY;
        gy1[h][g] = -INFINITY; gz0[h][g] = INFINITY; gz1[h][g] = -INFINITY;
      }
#pragma unroll
      for (int i = 0; i < 16; ++i) {
        int p = (int)s_perm[tid * 16 + i];
        int g = i >> 3;
        int s = h * 16 + i;
        px[s] = s_xyz[p * 3 + 0];
        py[s] = s_xyz[p * 3 + 1];
        pz[s] = s_xyz[p * 3 + 2];
        d[s] = INFINITY;   // fminf(inf, v) == v exactly -> first update installs d0
        lo32[s] = 0xFFFFFFFFu - (unsigned)p;
        gx0[h][g] = fminf(gx0[h][g], px[s]); gx1[h][g] = fmaxf(gx1[h][g], px[s]);
        gy0[h][g] = fminf(gy0[h][g], py[s]); gy1[h][g] = fmaxf(gy1[h][g], py[s]);
        gz0[h][g] = fminf(gz0[h][g], pz[s]); gz1[h][g] = fmaxf(gz1[h][g], pz[s]);
      }

      int fi = first_idx[b];
      ncx[h] = s_xyz[fi * 3 + 0]; ncy[h] = s_xyz[fi * 3 + 1]; ncz[h] = s_xyz[fi * 3 + 2];
      if (tid == 0) {
        float* r = (h ? s_ring1 : s_ring0);
        r[0] = ncx[h]; r[1] = ncy[h]; r[2] = ncz[h];
      }
      __syncthreads();   // s_xyz/perm/hist free for next half
    }

    unsigned long long gkey[2][2], wk[2];
    gkey[0][0] = 0x7F800000ULL << 32; gkey[0][1] = 0x7F800000ULL << 32;
    gkey[1][0] = 0x7F800000ULL << 32; gkey[1][1] = 0x7F800000ULL << 32;
    wk[0] = 0x7F800000ULL << 32; wk[1] = 0x7F800000ULL << 32;

    for (int it = 1; it < M_; ++it) {
      const int par = it & 1;
      // ---- pre-barrier: update + DPP reduce, both batches interleaved ----
#pragma unroll
      for (int h = 0; h < 2; ++h) {
        float nx = ncx[h], ny = ncy[h], nz = ncz[h];
        bool tr[2];
#pragma unroll
        for (int g = 0; g < 2; ++g) {
          float gdx = fmaxf(fmaxf(gx0[h][g] - nx, nx - gx1[h][g]), 0.f);
          float gdy = fmaxf(fmaxf(gy0[h][g] - ny, ny - gy1[h][g]), 0.f);
          float gdz = fmaxf(fmaxf(gz0[h][g] - nz, nz - gz1[h][g]), 0.f);
          float glb = __builtin_fmaf(gdz, gdz, __builtin_fmaf(gdy, gdy, gdx * gdx));
          float ggm = __builtin_bit_cast(float, (unsigned)(gkey[h][g] >> 32));
          tr[g] = glb * 0.999f < ggm;
        }
        if (__any(tr[0] || tr[1])) {
#pragma unroll
          for (int g = 0; g < 2; ++g) {
            if (tr[g]) {
              unsigned long long k[8];
#pragma unroll
              for (int i = 0; i < 8; ++i) {
                int s = h * 16 + g * 8 + i;
                float dd = d2fma(px[s], py[s], pz[s], nx, ny, nz);
                float dm = fminf(d[s], dd);
                d[s] = dm;
                k[i] = ((unsigned long long)__builtin_bit_cast(unsigned, dm) << 32) |
                       (unsigned long long)lo32[s];
              }
#pragma unroll
              for (int sd = 4; sd >= 1; sd >>= 1)
#pragma unroll
                for (int i = 0; i < sd; ++i)
                  k[i] = k[i] > k[i + sd] ? k[i] : k[i + sd];
              gkey[h][g] = k[0];
            }
          }
          unsigned long long kk = gkey[h][0] > gkey[h][1] ? gkey[h][0] : gkey[h][1];
          wk[h] = wave_dpp_max64(kk);
        }
        if (lane == 63) s_went[(par * 2 + h) * 8 + wv] = wk[h];
      }
      __syncthreads();

      // ---- publish chunk [it-32, it) for both batches (ring pre-barrier) --
      if ((it & 31) == 0) {
        if (wv < 2 && lane < 24) {
          const float* ring = (wv ? s_ring1 : s_ring0);
          const float4* src = (const float4*)(ring + ((it - 32) & 63) * 3);
          float4* dst = (float4*)(centers + (size_t)(2 * bp + wv) * M_ * 3 +
                                  (size_t)(it - 32) * 3);
          dst[lane] = src[lane];
        }
        if (lane == 0 && wv < 2)
          __hip_atomic_store(&prog[(2 * bp + wv) * 32], it, __ATOMIC_RELEASE,
                             __HIP_MEMORY_SCOPE_AGENT);
      }

      // ---- post-barrier: cross-wave trees, then both coord loads ----
      int gs[2];
#pragma unroll
      for (int h = 0; h < 2; ++h) {
        const ulonglong2* sp = (const ulonglong2*)(&s_went[(par * 2 + h) * 8]);
        ulonglong2 q0 = sp[0], q1 = sp[1], q2 = sp[2], q3 = sp[3];
        unsigned long long a0 = q0.x > q0.y ? q0.x : q0.y;
        unsigned long long a1 = q1.x > q1.y ? q1.x : q1.y;
        unsigned long long a2 = q2.x > q2.y ? q2.x : q2.y;
        unsigned long long a3 = q3.x > q3.y ? q3.x : q3.y;
        unsigned long long b0 = a0 > a1 ? a0 : a1;
        unsigned long long b1v = a2 > a3 ? a2 : a3;
        unsigned long long gk = b0 > b1v ? b0 : b1v;
        int gi = (int)(0xFFFFFFFFu - (unsigned)(gk & 0xFFFFFFFFull));
        gs[h] = __builtin_amdgcn_readfirstlane(gi);   // uniform index
      }
#pragma unroll
      for (int h = 0; h < 2; ++h) {
        const float* xw = x + ((size_t)(2 * bp + h) * N_ + gs[h]) * 3;  // == old s_xyz bits
        ncx[h] = xw[0]; ncy[h] = xw[1]; ncz[h] = xw[2];
        if (tid == 0) {
          float* r = (h ? s_ring1 : s_ring0) + (it & 63) * 3;
          r[0] = ncx[h]; r[1] = ncy[h]; r[2] = ncz[h];
        }
      }
      // no second barrier: next iteration writes the other parity entries
    }

    // final chunk (centers 2016..2047) + completion publish
    __syncthreads();
    if (wv < 2 && lane < 24) {
      const float* ring = (wv ? s_ring1 : s_ring0);
      const float4* src = (const float4*)(ring + ((M_ - 32) & 63) * 3);
      float4* dst = (float4*)(centers + (size_t)(2 * bp + wv) * M_ * 3 +
                              (size_t)(M_ - 32) * 3);
      dst[lane] = src[lane];
    }
    if (lane == 0 && wv < 2)
      __hip_atomic_store(&prog[(2 * bp + wv) * 32], M_, __ATOMIC_RELEASE,
                         __HIP_MEMORY_SCOPE_AGENT);

  } else {
    // ================ consumer: 2-center ballq + 64-row MLP ================
    unsigned short* A1 = (unsigned short*)smem;            // [64][104] bf16
    unsigned short* H1 = (unsigned short*)(smem + 13312);  // [64][296] bf16
    float* H2 = (float*)(smem + 51200);                    // [64][132] f32
    float* cd = (float*)(smem + 84992);                    // [2][512]
    int* cidx = (int*)(smem + 89088);                      // [2][512]
    float* s_sum = (float*)(smem + 93184);                 // [64]
    float* s_sum2 = (float*)(smem + 93440);                // [64]
    float* s_mu = (float*)(smem + 93696);                  // [64]
    float* s_rs = (float*)(smem + 93952);                  // [64]
    int* s_nbr = (int*)(smem + 94208);                     // [64]
    float* s_ctr = (float*)(smem + 94464);                 // [6]
    int* s_wc = (int*)(smem + 94496);                      // [2][8]

    const int j = (int)blockIdx.x - NPROD_; // 0..239
    const int b = j & 7;                    // owned batch
    const int c = j >> 3;                   // 0..29 within batch
    const int q4 = lane >> 4;  // quad 0..3
    const int nl = lane & 15;

    for (int e = tid; e < 64 * 104; e += 512) A1[e] = 0;
    for (int e = tid; e < 64 * 296; e += 512) H1[e] = 0;
    __syncthreads();

    const float* xb = x + (size_t)b * N_ * 3;

    for (int k35 = 0; k35 < 35; ++k35) {
      int i = c + 30 * k35;                 // pair index, block-uniform
      if (i >= 1024) break;
      const int m0 = 2 * i, m1 = m0 + 1;
      const int cm0 = b * M_ + m0;

      // wait until both centers are published. RELAXED polls (no L2 inval)
      // with an ACQUIRE refresh every 8th poll (progress guarantee), and a
      // final ACQUIRE before the barrier (synchronizes-with the release).
      if (tid == 0) {
        int v = __hip_atomic_load(&prog[b * 32], __ATOMIC_RELAXED,
                                  __HIP_MEMORY_SCOPE_AGENT);
        int spins = 0;
        while (v <= m1) {
          __builtin_amdgcn_s_sleep(32);
          v = ((++spins & 7) == 0)
                  ? __hip_atomic_load(&prog[b * 32], __ATOMIC_ACQUIRE,
                                      __HIP_MEMORY_SCOPE_AGENT)
                  : __hip_atomic_load(&prog[b * 32], __ATOMIC_RELAXED,
                                      __HIP_MEMORY_SCOPE_AGENT);
        }
        (void)__hip_atomic_load(&prog[b * 32], __ATOMIC_ACQUIRE,
                                __HIP_MEMORY_SCOPE_AGENT);
      }
      __syncthreads();

      if (tid < 64) s_sum[tid] = 0.f;
      else if (tid < 128) s_sum2[tid - 64] = 0.f;
      else if (tid < 134) s_ctr[tid - 128] = centers[(size_t)cm0 * 3 + (tid - 128)];
      __syncthreads();

      const float c0x = s_ctr[0], c0y = s_ctr[1], c0z = s_ctr[2];
      const float c1x = s_ctr[3], c1y = s_ctr[4], c1z = s_ctr[5];

      // ---- ball query, both centers, one x-scan (index-ordered, verified)
      int cnt0 = 0, cnt1 = 0;
      for (int s = 0; s < 16; ++s) {
        int p = wv * 1024 + s * 64 + lane;
        float X = xb[p * 3 + 0], Y = xb[p * 3 + 1], Z = xb[p * 3 + 2];
        float d20 = d2fma(X, Y, Z, c0x, c0y, c0z);
        float d21 = d2fma(X, Y, Z, c1x, c1y, c1z);
        cnt0 += (int)__popcll(__ballot(d20 < 0.09f));
        cnt1 += (int)__popcll(__ballot(d21 < 0.09f));
      }
      if (lane == 0) { s_wc[wv] = cnt0; s_wc[8 + wv] = cnt1; }
      __syncthreads();
      int base0 = 0, tot0 = 0, base1 = 0, tot1 = 0;
#pragma unroll
      for (int w = 0; w < 8; ++w) {
        int v0 = s_wc[w], v1 = s_wc[8 + w];
        base0 += (w < wv) ? v0 : 0; tot0 += v0;
        base1 += (w < wv) ? v1 : 0; tot1 += v1;
      }
      int count0 = tot0 < CAPQ_ ? tot0 : CAPQ_;
      int count1 = tot1 < CAPQ_ ? tot1 : CAPQ_;
      // pass 2: write (d2, idx) at exact global index-ordered positions
      int pos0 = base0, pos1 = base1;
      for (int s = 0; s < 16; ++s) {
        int p = wv * 1024 + s * 64 + lane;
        float X = xb[p * 3 + 0], Y = xb[p * 3 + 1], Z = xb[p * 3 + 2];
        float d20 = d2fma(X, Y, Z, c0x, c0y, c0z);
        float d21 = d2fma(X, Y, Z, c1x, c1y, c1z);
        bool in0 = d20 < 0.09f;   // f32(0.3**2), strict <
        bool in1 = d21 < 0.09f;
        unsigned long long m0m = __ballot(in0);
        unsigned long long m1m = __ballot(in1);
        if (in0) {
          int pp = pos0 + (int)__popcll(m0m & ((1ull << lane) - 1ull));
          if (pp < CAPQ_) { cd[pp] = d20; cidx[pp] = p; }
        }
        if (in1) {
          int pp = pos1 + (int)__popcll(m1m & ((1ull << lane) - 1ull));
          if (pp < CAPQ_) { cd[CAPQ_ + pp] = d21; cidx[CAPQ_ + pp] = p; }
        }
        pos0 += (int)__popcll(m0m);
        pos1 += (int)__popcll(m1m);
      }
      __syncthreads();
      // rank-select K nearest per center (stable order), 256 threads each
      {
        int q = tid >> 8;                  // 0 or 1
        int lt = tid & 255;
        int cnt = q ? count1 : count0;
        int nw = cnt < K_ ? cnt : K_;
        const float* cdq = cd + q * CAPQ_;
        const int* cxq = cidx + q * CAPQ_;
        for (int cc = lt; cc < cnt; cc += 256) {
          float dcc = cdq[cc];
          int rank = 0;
          for (int jj = 0; jj < cnt; ++jj) {
            float dj = cdq[jj];
            rank += (dj < dcc || (dj == dcc && jj < cc)) ? 1 : 0;  // stable
          }
          if (rank < K_) s_nbr[q * K_ + rank] = cxq[cc];
        }
        for (int s = nw + lt; s < K_; s += 256) s_nbr[q * K_ + s] = N_ - 1;
      }
      __syncthreads();

      // ---- gather: 16 threads per neighbor row, 64 rows in 2 halves
#pragma unroll
      for (int hh = 0; hh < 2; ++hh) {
        int rr = (tid >> 4) + hh * 32;     // row 0..63
        int jj = tid & 15;
        int q = rr >> 5;
        int idx = s_nbr[rr];
        const float4* frow = (const float4*)(features + ((size_t)b * N_ + idx) * C_);
        float4 f4 = frow[jj];
        int base = rr * 104 + jj * 4;
        A1[base + 0] = f2bf(f4.x); A1[base + 1] = f2bf(f4.y);
        A1[base + 2] = f2bf(f4.z); A1[base + 3] = f2bf(f4.w);
        if (jj == 0) {
          const float* xp = x + ((size_t)b * N_ + idx) * 3;
          A1[rr * 104 + 64] = f2bf(xp[0] - s_ctr[q * 3 + 0]);
          A1[rr * 104 + 65] = f2bf(xp[1] - s_ctr[q * 3 + 1]);
          A1[rr * 104 + 66] = f2bf(xp[2] - s_ctr[q * 3 + 2]);
        }
      }
      __syncthreads();

      // GEMM1: (64x96) @ (96x272), B-frags register-cached from global
      for (int nt = wv; nt < 17; nt += 8) {
        short8 bfr[3];
#pragma unroll
        for (int kt = 0; kt < 3; ++kt)
          bfr[kt] = *(const short8*)(w1p + (size_t)((kt * 17 + nt) * 64 + lane) * 8);
        int col = nt * 16 + nl;
        bool cok = col < HID_;
        float bias = cok ? b1[col] : 0.f;
#pragma unroll
        for (int mt = 0; mt < 4; ++mt) {
          floatx4 acc = {0.f, 0.f, 0.f, 0.f};
          const unsigned short* ap = A1 + (mt * 16 + nl) * 104 + q4 * 8;
#pragma unroll
          for (int kt = 0; kt < 3; ++kt) {
            short8 a = *(const short8*)(ap + kt * 32);
            acc = __builtin_amdgcn_mfma_f32_16x16x32_bf16(a, bfr[kt], acc, 0, 0, 0);
          }
#pragma unroll
          for (int r = 0; r < 4; ++r) {
            int row = mt * 16 + q4 * 4 + r;
            float g = 0.f;
            if (cok) {
              float v = acc[r] + bias;
              g = gelu_tanh(v);
              H1[row * 296 + col] = f2bf(g);
            }
            float s1 = g, s2 = g * g;
#pragma unroll
            for (int off = 1; off < 16; off <<= 1) {
              s1 += __shfl_xor(s1, off);
              s2 += __shfl_xor(s2, off);
            }
            if (nl == 0) { atomicAdd(&s_sum[row], s1); atomicAdd(&s_sum2[row], s2); }
          }
        }
      }
      __syncthreads();
      if (tid < 64) {
        float mu = s_sum[tid] * (1.f / HID_);
        float var = s_sum2[tid] * (1.f / HID_) - mu * mu;
        s_mu[tid] = mu;
        s_rs[tid] = rsqrtf(var + EPS_);
      }
      __syncthreads();
      // LN1 in place (bf16), zero stats for LN2
      for (int e = tid; e < 64 * HID_; e += 512) {
        int r = e / HID_, cc = e - r * HID_;
        float g = bf2f(H1[r * 296 + cc]);
        float v = (g - s_mu[r]) * s_rs[r] * g1[cc] + be1[cc];
        H1[r * 296 + cc] = f2bf(v);
      }
      if (tid < 64) { s_sum[tid] = 0.f; s_sum2[tid] = 0.f; }
      __syncthreads();

      // GEMM2: (64x288) @ (288x128), one n-tile per wave
      {
        int nt = wv;
        short8 bfr2[9];
#pragma unroll
        for (int kt = 0; kt < 9; ++kt)
          bfr2[kt] = *(const short8*)(w2p + (size_t)((kt * 8 + nt) * 64 + lane) * 8);
        int col = nt * 16 + nl;
        float bias = b2[col];
#pragma unroll
        for (int mt = 0; mt < 4; ++mt) {
          floatx4 acc = {0.f, 0.f, 0.f, 0.f};
          const unsigned short* ap = H1 + (mt * 16 + nl) * 296 + q4 * 8;
#pragma unroll
          for (int kt = 0; kt < 9; ++kt) {
            short8 a = *(const short8*)(ap + kt * 32);
            acc = __builtin_amdgcn_mfma_f32_16x16x32_bf16(a, bfr2[kt], acc, 0, 0, 0);
          }
#pragma unroll
          for (int r = 0; r < 4; ++r) {
            int row = mt * 16 + q4 * 4 + r;
            float v = acc[r] + bias;
            H2[row * 132 + col] = v;
            float s1 = v, s2 = v * v;
#pragma unroll
            for (int off = 1; off < 16; off <<= 1) {
              s1 += __shfl_xor(s1, off);
              s2 += __shfl_xor(s2, off);
            }
            if (nl == 0) { atomicAdd(&s_sum[row], s1); atomicAdd(&s_sum2[row], s2); }
          }
        }
      }
      __syncthreads();
      if (tid < 64) {
        float mu = s_sum[tid] * (1.f / OUT_);
        float var = s_sum2[tid] * (1.f / OUT_) - mu * mu;
        s_mu[tid] = mu;
        s_rs[tid] = rsqrtf(var + EPS_);
      }
      __syncthreads();
      if (tid < 256) {
        int q = tid >> 7, col = tid & 127;
        float gg = g2[col], bb = be2[col];
        float mx = -3.4e38f;
#pragma unroll 4
        for (int r = 0; r < K_; ++r) {
          int row = q * K_ + r;
          float v = H2[row * 132 + col];
          float o = (v - s_mu[row]) * s_rs[row] * gg + bb;
          mx = fmaxf(mx, o);
        }
        out1[(size_t)(cm0 + q) * OUT_ + col] = mx;   // FLOAT32 output
      }
      __syncthreads();
    }
  }
}

extern "C" void kernel_launch(void* const* d_in, const int* in_sizes, int n_in,
                              void* d_out, int out_size, void* d_ws, size_t ws_size,
                              hipStream_t stream) {
  const float* x = (const float*)d_in[0];
  const float* features = (const float*)d_in[1];
  const int* first_idx = (const int*)d_in[2];
  const float* w1 = (const float*)d_in[3];
  const float* b1 = (const float*)d_in[4];
  const float* g1 = (const float*)d_in[5];
  const float* be1 = (const float*)d_in[6];
  const float* w2 = (const float*)d_in[7];
  const float* b2 = (const float*)d_in[8];
  const float* g2 = (const float*)d_in[9];
  const float* be2 = (const float*)d_in[10];

  // d_out is FLOAT32: centers (8,2048,3) then out (8,2048,128), concatenated.
  float* centers = (float*)d_out;
  float* out1 = (float*)d_out + (size_t)B_ * M_ * 3;

  // ws layout (bytes): prog [0,1024) cacheline-padded (stride 32 ints/batch) |
  //                    w1p [2097152,2149376) | w2p [2149376,2223104)
  int* prog = (int*)d_ws;
  unsigned short* w1p = (unsigned short*)((char*)d_ws + 2097152);
  unsigned short* w2p = (unsigned short*)((char*)d_ws + 2149376);

  pack_kernel<<<dim3(246), dim3(256), 0, stream>>>(w1, w2, w1p, w2p, prog);
  fused_kernel<<<dim3(NPROD_ + CONS_), dim3(512), 0, stream>>>(
      x, features, first_idx, w1p, b1, g1, be1, w2p, b2, g2, be2,
      centers, out1, prog);
}

// Round 6
// 2794.997 us; speedup vs baseline: 1.0990x; 1.0990x over previous
//
#include <hip/hip_runtime.h>
#include <hip/hip_bf16.h>
#include <math.h>

#define B_ 8
#define N_ 8192
#define C_ 64
#define M_ 2048
#define K_ 32
#define OUT_ 128
#define CIN_ 67
#define HID_ 268
#define EPS_ 1e-6f
#define CONS_ 240      // 8 batches x 30 consumers
#define CAPQ_ 512

typedef short short8 __attribute__((ext_vector_type(8)));
typedef float floatx4 __attribute__((ext_vector_type(4)));
typedef unsigned long long ull;

__device__ __forceinline__ unsigned short f2bf(float f) {
  unsigned u = __builtin_bit_cast(unsigned, f);
  u += 0x7fffu + ((u >> 16) & 1u);   // RNE (MFMA input casts only)
  return (unsigned short)(u >> 16);
}
__device__ __forceinline__ float bf2f(unsigned short h) {
  return __builtin_bit_cast(float, (unsigned)h << 16);
}

// Reference-matching distance (verified r13, bit-exact).
__device__ __forceinline__ float d2fma(float ax, float ay, float az,
                                       float bx, float by, float bz) {
#pragma clang fp contract(off)
  float dx = ax - bx, dy = ay - by, dz = az - bz;
  return __builtin_fmaf(dz, dz, __builtin_fmaf(dy, dy, dx * dx));
}

__device__ __forceinline__ float gelu_tanh(float v) {
  const float k0 = 0.7978845608028654f;  // sqrt(2/pi)
  const float k1 = 0.044715f;
  float u = k0 * (v + k1 * v * v * v);
  return 0.5f * v * (1.0f + tanhf(u));
}

// Morton spread of a 4-bit value to bit positions 0,3,6,9
__device__ __forceinline__ int msp4(int v) {
  return (v & 1) | ((v & 2) << 2) | ((v & 4) << 4) | ((v & 8) << 6);
}

// top-2 merge: (a1,a2) := top2 of {a1,a2,b1,b2}, given a1>=a2, b1>=b2.
// Keys are unique (idx in low bits) so strict order is total.
__device__ __forceinline__ void top2_merge(ull &a1, ull &a2, ull b1, ull b2) {
  bool c = a1 > b1;
  ull h = c ? a1 : b1;
  ull l = c ? b1 : a1;
  ull s = c ? a2 : b2;
  ull sec = l > s ? l : s;
  a1 = h; a2 = sec;
}

template <int CTRL>
__device__ __forceinline__ ull dpp_mov64(ull k) {
  int lo = (int)(unsigned)k;
  int hi = (int)(unsigned)(k >> 32);
  unsigned slo = (unsigned)__builtin_amdgcn_update_dpp(0, lo, CTRL, 0xF, 0xF, true);
  unsigned shi = (unsigned)__builtin_amdgcn_update_dpp(0, hi, CTRL, 0xF, 0xF, true);
  return ((ull)shi << 32) | (ull)slo;   // bound_ctrl zero-fill = identity (keys>0)
}

template <int CTRL>
__device__ __forceinline__ void dpp_top2(ull &a1, ull &a2) {
  ull b1 = dpp_mov64<CTRL>(a1);
  ull b2 = dpp_mov64<CTRL>(a2);
  top2_merge(a1, a2, b1, b2);
}

// wave top-2 (valid in lane63; each source lane enters the lane63 lineage
// exactly once -> no duplicate element in {K1,K2})
__device__ __forceinline__ void wave_dpp_top2(ull &k1, ull &k2) {
  dpp_top2<0x111>(k1, k2);   // row_shr:1
  dpp_top2<0x112>(k1, k2);   // row_shr:2
  dpp_top2<0x114>(k1, k2);   // row_shr:4
  dpp_top2<0x118>(k1, k2);   // row_shr:8
  dpp_top2<0x142>(k1, k2);   // row_bcast:15
  dpp_top2<0x143>(k1, k2);   // row_bcast:31
}

// ---------------- Pack f32 weights into MFMA B-fragment order (bf16) ------
__global__ __launch_bounds__(256) void pack_kernel(
    const float* __restrict__ w1, const float* __restrict__ w2,
    unsigned short* __restrict__ w1p, unsigned short* __restrict__ w2p,
    int* __restrict__ prog) {
  if (blockIdx.x == 0) prog[threadIdx.x] = 0;   // 256 ints = 8 padded lines
  int e = blockIdx.x * 256 + threadIdx.x;
  if (e < 3 * 17 * 64 * 8) {
    int j = e & 7, lane = (e >> 3) & 63, fi = e >> 9;
    int kt = fi / 17, nt = fi - kt * 17;
    int k = kt * 32 + (lane >> 4) * 8 + j;
    int n = nt * 16 + (lane & 15);
    float v = (k < CIN_ && n < HID_) ? w1[k * HID_ + n] : 0.f;
    w1p[e] = f2bf(v);
  } else {
    int e2 = e - 3 * 17 * 64 * 8;
    if (e2 < 9 * 8 * 64 * 8) {
      int j = e2 & 7, lane = (e2 >> 3) & 63, fi = e2 >> 9;
      int kt = fi >> 3, nt = fi & 7;
      int k = kt * 32 + (lane >> 4) * 8 + j;
      int n = nt * 16 + (lane & 15);
      float v = (k < HID_) ? w2[k * OUT_ + n] : 0.f;
      w2p[e2] = f2bf(v);
    }
  }
}

// ---------------- Fused producer (FPS, double-select) + consumer ----------
// Blocks 0..7: FPS with top-2 reduction. Per round: apply pending 1-2
// center min-updates (bit-exact order W1-then-R; group-bbox skips are
// provable no-ops), DPP top-2 per wave, barrier, 8-slot top-2 tree ->
// {K1,K2}. Select W1=K1's point; additionally select R=K2's point iff
// dist2(R,W1) >= d(R) (then fminf leaves R's key bit-identical and all
// other keys stay < K2 -> R is exactly the reference's next argmax).
// Publishing: wave0 flushes s_cbuf chunks of 32 + release-stores prog.
// Blocks 8..247: consumers (R4-verified 2-center passes). All polls and
// center reads are RELAXED agent atomics (coherence-point reads, NO
// buffer_inv) -- removes the L2-invalidation storm/outlier.
__global__ __launch_bounds__(512) void fused_kernel(
    const float* __restrict__ x, const float* __restrict__ features,
    const int* __restrict__ first_idx,
    const unsigned short* __restrict__ w1p, const float* __restrict__ b1,
    const float* __restrict__ g1, const float* __restrict__ be1,
    const unsigned short* __restrict__ w2p, const float* __restrict__ b2,
    const float* __restrict__ g2, const float* __restrict__ be2,
    float* __restrict__ centers, float* __restrict__ out1,
    int* __restrict__ prog) {
  __shared__ __align__(16) char smem[133632];
  const int tid = threadIdx.x;
  const int lane = tid & 63;
  const int wv = tid >> 6;   // wave 0..7

  if (blockIdx.x < B_) {
    // ======================= FPS producer =======================
    const int b = blockIdx.x;
    const float* xb = x + (size_t)b * N_ * 3;

    float* s_xyz = (float*)smem;                                   // 98304 B
    char* s_mem = smem + 98304;                                    // 32768 B
    ulonglong2* s_went = (ulonglong2*)(smem + 131072);             // [2][8] 256B
    int* s_wsum = (int*)(smem + 131328);                           // 8
    float* s_bb = (float*)(smem + 131360);                         // [8][6]

    int* s_hist = (int*)s_mem;                                     // 4096 ints
    unsigned short* s_perm = (unsigned short*)(s_mem + 16384);     // 8192 shorts
    float* s_cbuf = (float*)s_mem;                                 // 6144 f (after sort)

    // stage coords: 6144 float4, coalesced, 12 per thread
    {
      const float4* src = (const float4*)xb;
      float4* dst = (float4*)s_xyz;
#pragma unroll
      for (int i = 0; i < 12; ++i) {
        int e = tid + i * 512;
        dst[e] = src[e];
      }
    }
    for (int i = tid; i < 4096; i += 512) s_hist[i] = 0;
    __syncthreads();

    // ---- batch bbox (binning only) ----
    float bx0 = INFINITY, bx1 = -INFINITY, by0 = INFINITY, by1 = -INFINITY,
          bz0 = INFINITY, bz1 = -INFINITY;
#pragma unroll
    for (int i = 0; i < 16; ++i) {
      int p = tid + i * 512;
      float X = s_xyz[p * 3 + 0], Y = s_xyz[p * 3 + 1], Z = s_xyz[p * 3 + 2];
      bx0 = fminf(bx0, X); bx1 = fmaxf(bx1, X);
      by0 = fminf(by0, Y); by1 = fmaxf(by1, Y);
      bz0 = fminf(bz0, Z); bz1 = fmaxf(bz1, Z);
    }
#pragma unroll
    for (int off = 1; off < 64; off <<= 1) {
      bx0 = fminf(bx0, __shfl_xor(bx0, off)); bx1 = fmaxf(bx1, __shfl_xor(bx1, off));
      by0 = fminf(by0, __shfl_xor(by0, off)); by1 = fmaxf(by1, __shfl_xor(by1, off));
      bz0 = fminf(bz0, __shfl_xor(bz0, off)); bz1 = fmaxf(bz1, __shfl_xor(bz1, off));
    }
    if (lane == 0) {
      s_bb[wv * 6 + 0] = bx0; s_bb[wv * 6 + 1] = bx1; s_bb[wv * 6 + 2] = by0;
      s_bb[wv * 6 + 3] = by1; s_bb[wv * 6 + 4] = bz0; s_bb[wv * 6 + 5] = bz1;
    }
    __syncthreads();
#pragma unroll
    for (int w = 0; w < 8; ++w) {
      bx0 = fminf(bx0, s_bb[w * 6 + 0]); bx1 = fmaxf(bx1, s_bb[w * 6 + 1]);
      by0 = fminf(by0, s_bb[w * 6 + 2]); by1 = fmaxf(by1, s_bb[w * 6 + 3]);
      bz0 = fminf(bz0, s_bb[w * 6 + 4]); bz1 = fmaxf(bz1, s_bb[w * 6 + 5]);
    }
    const float kS = 16.0f * (1.0f - 1e-6f);
    float rx = bx1 - bx0, ry = by1 - by0, rz = bz1 - bz0;
    float sxv = rx > 0.f ? kS / rx : 0.f;
    float syv = ry > 0.f ? kS / ry : 0.f;
    float szv = rz > 0.f ? kS / rz : 0.f;

    // ---- histogram (12-bit Morton cells) ----
#pragma unroll
    for (int i = 0; i < 16; ++i) {
      int p = tid + i * 512;
      int qx = (int)((s_xyz[p * 3 + 0] - bx0) * sxv);
      int qy = (int)((s_xyz[p * 3 + 1] - by0) * syv);
      int qz = (int)((s_xyz[p * 3 + 2] - bz0) * szv);
      qx = qx < 0 ? 0 : (qx > 15 ? 15 : qx);
      qy = qy < 0 ? 0 : (qy > 15 ? 15 : qy);
      qz = qz < 0 ? 0 : (qz > 15 ? 15 : qz);
      int c = msp4(qx) | (msp4(qy) << 1) | (msp4(qz) << 2);
      atomicAdd(&s_hist[c], 1);
    }
    __syncthreads();

    // ---- exclusive scan over 4096 bins ----
    {
      int h[8], pre[8];
      int acc = 0;
#pragma unroll
      for (int i = 0; i < 8; ++i) { h[i] = s_hist[tid * 8 + i]; pre[i] = acc; acc += h[i]; }
      int incl = acc;
#pragma unroll
      for (int off = 1; off < 64; off <<= 1) {
        int v = __shfl_up(incl, off);
        if (lane >= off) incl += v;
      }
      int texcl = incl - acc;
      if (lane == 63) s_wsum[wv] = incl;
      __syncthreads();
      int woff = 0;
#pragma unroll
      for (int w = 0; w < 8; ++w) woff += (w < wv) ? s_wsum[w] : 0;
#pragma unroll
      for (int i = 0; i < 8; ++i) s_hist[tid * 8 + i] = woff + texcl + pre[i];
    }
    __syncthreads();

    // ---- scatter ----
#pragma unroll
    for (int i = 0; i < 16; ++i) {
      int p = tid + i * 512;
      int qx = (int)((s_xyz[p * 3 + 0] - bx0) * sxv);
      int qy = (int)((s_xyz[p * 3 + 1] - by0) * syv);
      int qz = (int)((s_xyz[p * 3 + 2] - bz0) * szv);
      qx = qx < 0 ? 0 : (qx > 15 ? 15 : qx);
      qy = qy < 0 ? 0 : (qy > 15 ? 15 : qy);
      qz = qz < 0 ? 0 : (qz > 15 ? 15 : qz);
      int c = msp4(qx) | (msp4(qy) << 1) | (msp4(qz) << 2);
      int pos = atomicAdd(&s_hist[c], 1);
      s_perm[pos] = (unsigned short)p;
    }
    __syncthreads();

    // ---- 16 sorted slots/thread; 2 group bboxes of 8 ----
    float px[16], py[16], pz[16], d[16];
    unsigned lo32[16];
    float gx0[2], gx1[2], gy0[2], gy1[2], gz0[2], gz1[2];
#pragma unroll
    for (int g = 0; g < 2; ++g) {
      gx0[g] = INFINITY; gx1[g] = -INFINITY; gy0[g] = INFINITY;
      gy1[g] = -INFINITY; gz0[g] = INFINITY; gz1[g] = -INFINITY;
    }
#pragma unroll
    for (int i = 0; i < 16; ++i) {
      int p = (int)s_perm[tid * 16 + i];
      int g = i >> 3;
      px[i] = s_xyz[p * 3 + 0];
      py[i] = s_xyz[p * 3 + 1];
      pz[i] = s_xyz[p * 3 + 2];
      d[i] = INFINITY;   // fminf(inf, v) == v exactly
      lo32[i] = 0xFFFFFFFFu - (unsigned)p;
      gx0[g] = fminf(gx0[g], px[i]); gx1[g] = fmaxf(gx1[g], px[i]);
      gy0[g] = fminf(gy0[g], py[i]); gy1[g] = fmaxf(gy1[g], py[i]);
      gz0[g] = fminf(gz0[g], pz[i]); gz1[g] = fmaxf(gz1[g], pz[i]);
    }

    int fi = first_idx[b];
    float c0x = s_xyz[fi * 3 + 0], c0y = s_xyz[fi * 3 + 1], c0z = s_xyz[fi * 3 + 2];
    float c1x = 0.f, c1y = 0.f, c1z = 0.f;
    int npend = 1;
    int produced = 1;
    int nf = 0;                       // flushed-up-to (wave 0 uses it)
    if (tid == 0) { s_cbuf[0] = c0x; s_cbuf[1] = c0y; s_cbuf[2] = c0z; }

    ull gk1[2], gk2[2];
    gk1[0] = gk1[1] = gk2[0] = gk2[1] = 0x7F800000ULL << 32;   // sentinel inf
    ull wk1 = gk1[0], wk2 = gk1[0];
    int par = 0;

    for (;;) {
      par ^= 1;
      // ---- update phase: apply pending centers (W1 then R order) ----
      if (produced < M_) {
        bool t1[2], t2[2];
        bool anyt = false;
#pragma unroll
        for (int g = 0; g < 2; ++g) {
          float ggm = __builtin_bit_cast(float, (unsigned)(gk1[g] >> 32));
          float a = fmaxf(fmaxf(gx0[g] - c0x, c0x - gx1[g]), 0.f);
          float bq = fmaxf(fmaxf(gy0[g] - c0y, c0y - gy1[g]), 0.f);
          float cq = fmaxf(fmaxf(gz0[g] - c0z, c0z - gz1[g]), 0.f);
          float lb0 = __builtin_fmaf(cq, cq, __builtin_fmaf(bq, bq, a * a));
          t1[g] = lb0 * 0.999f < ggm;
          t2[g] = false;
          if (npend == 2) {
            float a2 = fmaxf(fmaxf(gx0[g] - c1x, c1x - gx1[g]), 0.f);
            float b2q = fmaxf(fmaxf(gy0[g] - c1y, c1y - gy1[g]), 0.f);
            float c2q = fmaxf(fmaxf(gz0[g] - c1z, c1z - gz1[g]), 0.f);
            float lb1 = __builtin_fmaf(c2q, c2q, __builtin_fmaf(b2q, b2q, a2 * a2));
            t2[g] = lb1 * 0.999f < ggm;
          }
          anyt = anyt || t1[g] || t2[g];
        }
        if (__any(anyt)) {
#pragma unroll
          for (int g = 0; g < 2; ++g) {
            if (t1[g] || t2[g]) {
              ull k[8];
#pragma unroll
              for (int i = 0; i < 8; ++i) {
                int s = g * 8 + i;
                float dm = d[s];
                if (t1[g]) dm = fminf(dm, d2fma(px[s], py[s], pz[s], c0x, c0y, c0z));
                if (t2[g]) dm = fminf(dm, d2fma(px[s], py[s], pz[s], c1x, c1y, c1z));
                d[s] = dm;
                k[i] = ((ull)__builtin_bit_cast(unsigned, dm) << 32) | (ull)lo32[s];
              }
              // group top-2 (distinct keys)
              ull m0 = k[0] > k[1] ? k[0] : k[1], n0 = k[0] > k[1] ? k[1] : k[0];
              ull m1 = k[2] > k[3] ? k[2] : k[3], n1 = k[2] > k[3] ? k[3] : k[2];
              ull m2 = k[4] > k[5] ? k[4] : k[5], n2 = k[4] > k[5] ? k[5] : k[4];
              ull m3 = k[6] > k[7] ? k[6] : k[7], n3 = k[6] > k[7] ? k[7] : k[6];
              top2_merge(m0, n0, m1, n1);
              top2_merge(m2, n2, m3, n3);
              top2_merge(m0, n0, m2, n2);
              gk1[g] = m0; gk2[g] = n0;
            }
          }
          ull a1 = gk1[0], a2 = gk2[0];
          top2_merge(a1, a2, gk1[1], gk2[1]);
          wave_dpp_top2(a1, a2);
          wk1 = a1; wk2 = a2;    // lane63 holds the wave's exact top-2
        }
        if (lane == 63) {
          ulonglong2 sl; sl.x = wk1; sl.y = wk2;
          s_went[par * 8 + wv] = sl;
        }
      }
      __syncthreads();
      if (produced >= M_) break;    // uniform: all waves computed 'produced'

      // ---- selection: exact global top-2 from 8 wave pairs ----
      ull K1, K2;
      {
        const ulonglong2* sp = &s_went[par * 8];
        ulonglong2 s0 = sp[0];
        K1 = s0.x; K2 = s0.y;
#pragma unroll
        for (int w = 1; w < 8; ++w) {
          ulonglong2 sw = sp[w];
          top2_merge(K1, K2, sw.x, sw.y);
        }
      }
      int i1 = (int)(0xFFFFFFFFu - (unsigned)(K1 & 0xFFFFFFFFull));
      int i2 = (int)(0xFFFFFFFFu - (unsigned)(K2 & 0xFFFFFFFFull));
      int u1 = __builtin_amdgcn_readfirstlane(i1);
      int u2 = __builtin_amdgcn_readfirstlane(i2);
      float w1x = s_xyz[u1 * 3 + 0], w1y = s_xyz[u1 * 3 + 1], w1z = s_xyz[u1 * 3 + 2];
      float rxx = s_xyz[u2 * 3 + 0], ryy = s_xyz[u2 * 3 + 1], rzz = s_xyz[u2 * 3 + 2];
      float dR = __builtin_bit_cast(float, (unsigned)(K2 >> 32));
      float dd = d2fma(rxx, ryy, rzz, w1x, w1y, w1z);
      // If min(dR, dd) == dR bitwise (dd >= dR), R is exactly the next argmax.
      bool two = (dd >= dR) && (produced + 2 <= M_);
      if (tid == 0) {
        s_cbuf[produced * 3 + 0] = w1x;
        s_cbuf[produced * 3 + 1] = w1y;
        s_cbuf[produced * 3 + 2] = w1z;
        if (two) {
          s_cbuf[produced * 3 + 3] = rxx;
          s_cbuf[produced * 3 + 4] = ryy;
          s_cbuf[produced * 3 + 5] = rzz;
        }
      }
      produced += two ? 2 : 1;
      // pending centers for next round's update (W1 then R order)
      c0x = w1x; c0y = w1y; c0z = w1z;
      if (two) { c1x = rxx; c1y = ryy; c1z = rzz; npend = 2; }
      else npend = 1;
      // ---- publish by wave 0 (all s_cbuf writes are lane0-of-wave0:
      //      wave-internal LDS ordering makes the flush reads safe) ----
      if (wv == 0) {
        while (nf + 32 <= produced) {
          if (lane < 24) {
            const float4* src = (const float4*)(s_cbuf + (size_t)nf * 3);
            float4* dst = (float4*)(centers + (size_t)b * M_ * 3 + (size_t)nf * 3);
            dst[lane] = src[lane];
          }
          nf += 32;
          if (lane == 0)
            __hip_atomic_store(&prog[b * 32], nf, __ATOMIC_RELEASE,
                               __HIP_MEMORY_SCOPE_AGENT);
        }
      }
    }

    // tail flush (entries were written by lane0-of-wave0; barrier crossed)
    if (wv == 0) {
      while (nf < M_) {
        if (lane < 24) {
          const float4* src = (const float4*)(s_cbuf + (size_t)nf * 3);
          float4* dst = (float4*)(centers + (size_t)b * M_ * 3 + (size_t)nf * 3);
          dst[lane] = src[lane];
        }
        nf += 32;
      }
      if (lane == 0)
        __hip_atomic_store(&prog[b * 32], M_, __ATOMIC_RELEASE,
                           __HIP_MEMORY_SCOPE_AGENT);
    }

  } else {
    // ================ consumer: 2-center ballq + 64-row MLP ================
    unsigned short* A1 = (unsigned short*)smem;            // [64][104] bf16
    unsigned short* H1 = (unsigned short*)(smem + 13312);  // [64][296] bf16
    float* H2 = (float*)(smem + 51200);                    // [64][132] f32
    float* cd = (float*)(smem + 84992);                    // [2][512]
    int* cidx = (int*)(smem + 89088);                      // [2][512]
    float* s_sum = (float*)(smem + 93184);                 // [64]
    float* s_sum2 = (float*)(smem + 93440);                // [64]
    float* s_mu = (float*)(smem + 93696);                  // [64]
    float* s_rs = (float*)(smem + 93952);                  // [64]
    int* s_nbr = (int*)(smem + 94208);                     // [64]
    float* s_ctr = (float*)(smem + 94464);                 // [6]
    int* s_wc = (int*)(smem + 94496);                      // [2][8]

    const int j = (int)blockIdx.x - B_;     // 0..239
    const int b = j & 7;                    // owned batch
    const int c = j >> 3;                   // 0..29 within batch
    const int q4 = lane >> 4;  // quad 0..3
    const int nl = lane & 15;

    for (int e = tid; e < 64 * 104; e += 512) A1[e] = 0;
    for (int e = tid; e < 64 * 296; e += 512) H1[e] = 0;
    __syncthreads();

    const float* xb = x + (size_t)b * N_ * 3;

    for (int k35 = 0; k35 < 35; ++k35) {
      int i = c + 30 * k35;                 // pair index, block-uniform
      if (i >= 1024) break;
      const int m0 = 2 * i, m1 = m0 + 1;
      const int cm0 = b * M_ + m0;

      // RELAXED agent polls: coherence-point reads, NO cache invalidation.
      if (tid == 0) {
        while (__hip_atomic_load(&prog[b * 32], __ATOMIC_RELAXED,
                                 __HIP_MEMORY_SCOPE_AGENT) <= m1)
          __builtin_amdgcn_s_sleep(32);
      }
      __syncthreads();

      if (tid < 64) s_sum[tid] = 0.f;
      else if (tid < 128) s_sum2[tid - 64] = 0.f;
      else if (tid < 134) {
        // bypassing reads of the 6 center words (producer release-flushed
        // them to the coherence point before bumping prog)
        unsigned wrd = __hip_atomic_load(
            (const unsigned*)&centers[(size_t)cm0 * 3 + (tid - 128)],
            __ATOMIC_RELAXED, __HIP_MEMORY_SCOPE_AGENT);
        s_ctr[tid - 128] = __builtin_bit_cast(float, wrd);
      }
      __syncthreads();

      const float c0x = s_ctr[0], c0y = s_ctr[1], c0z = s_ctr[2];
      const float c1x = s_ctr[3], c1y = s_ctr[4], c1z = s_ctr[5];

      // ---- ball query, both centers, one x-scan (index-ordered, verified)
      int cnt0 = 0, cnt1 = 0;
      for (int s = 0; s < 16; ++s) {
        int p = wv * 1024 + s * 64 + lane;
        float X = xb[p * 3 + 0], Y = xb[p * 3 + 1], Z = xb[p * 3 + 2];
        float d20 = d2fma(X, Y, Z, c0x, c0y, c0z);
        float d21 = d2fma(X, Y, Z, c1x, c1y, c1z);
        cnt0 += (int)__popcll(__ballot(d20 < 0.09f));
        cnt1 += (int)__popcll(__ballot(d21 < 0.09f));
      }
      if (lane == 0) { s_wc[wv] = cnt0; s_wc[8 + wv] = cnt1; }
      __syncthreads();
      int base0 = 0, tot0 = 0, base1 = 0, tot1 = 0;
#pragma unroll
      for (int w = 0; w < 8; ++w) {
        int v0 = s_wc[w], v1 = s_wc[8 + w];
        base0 += (w < wv) ? v0 : 0; tot0 += v0;
        base1 += (w < wv) ? v1 : 0; tot1 += v1;
      }
      int count0 = tot0 < CAPQ_ ? tot0 : CAPQ_;
      int count1 = tot1 < CAPQ_ ? tot1 : CAPQ_;
      int pos0 = base0, pos1 = base1;
      for (int s = 0; s < 16; ++s) {
        int p = wv * 1024 + s * 64 + lane;
        float X = xb[p * 3 + 0], Y = xb[p * 3 + 1], Z = xb[p * 3 + 2];
        float d20 = d2fma(X, Y, Z, c0x, c0y, c0z);
        float d21 = d2fma(X, Y, Z, c1x, c1y, c1z);
        bool in0 = d20 < 0.09f;   // f32(0.3**2), strict <
        bool in1 = d21 < 0.09f;
        unsigned long long m0m = __ballot(in0);
        unsigned long long m1m = __ballot(in1);
        if (in0) {
          int pp = pos0 + (int)__popcll(m0m & ((1ull << lane) - 1ull));
          if (pp < CAPQ_) { cd[pp] = d20; cidx[pp] = p; }
        }
        if (in1) {
          int pp = pos1 + (int)__popcll(m1m & ((1ull << lane) - 1ull));
          if (pp < CAPQ_) { cd[CAPQ_ + pp] = d21; cidx[CAPQ_ + pp] = p; }
        }
        pos0 += (int)__popcll(m0m);
        pos1 += (int)__popcll(m1m);
      }
      __syncthreads();
      // rank-select K nearest per center (stable order), 256 threads each
      {
        int q = tid >> 8;                  // 0 or 1
        int lt = tid & 255;
        int cnt = q ? count1 : count0;
        int nw = cnt < K_ ? cnt : K_;
        const float* cdq = cd + q * CAPQ_;
        const int* cxq = cidx + q * CAPQ_;
        for (int cc = lt; cc < cnt; cc += 256) {
          float dcc = cdq[cc];
          int rank = 0;
          for (int jj = 0; jj < cnt; ++jj) {
            float dj = cdq[jj];
            rank += (dj < dcc || (dj == dcc && jj < cc)) ? 1 : 0;  // stable
          }
          if (rank < K_) s_nbr[q * K_ + rank] = cxq[cc];
        }
        for (int s = nw + lt; s < K_; s += 256) s_nbr[q * K_ + s] = N_ - 1;
      }
      __syncthreads();

      // ---- gather: 16 threads per neighbor row, 64 rows in 2 halves
#pragma unroll
      for (int hh = 0; hh < 2; ++hh) {
        int rr = (tid >> 4) + hh * 32;     // row 0..63
        int jj = tid & 15;
        int q = rr >> 5;
        int idx = s_nbr[rr];
        const float4* frow = (const float4*)(features + ((size_t)b * N_ + idx) * C_);
        float4 f4 = frow[jj];
        int base = rr * 104 + jj * 4;
        A1[base + 0] = f2bf(f4.x); A1[base + 1] = f2bf(f4.y);
        A1[base + 2] = f2bf(f4.z); A1[base + 3] = f2bf(f4.w);
        if (jj == 0) {
          const float* xp = x + ((size_t)b * N_ + idx) * 3;
          A1[rr * 104 + 64] = f2bf(xp[0] - s_ctr[q * 3 + 0]);
          A1[rr * 104 + 65] = f2bf(xp[1] - s_ctr[q * 3 + 1]);
          A1[rr * 104 + 66] = f2bf(xp[2] - s_ctr[q * 3 + 2]);
        }
      }
      __syncthreads();

      // GEMM1: (64x96) @ (96x272)
      for (int nt = wv; nt < 17; nt += 8) {
        short8 bfr[3];
#pragma unroll
        for (int kt = 0; kt < 3; ++kt)
          bfr[kt] = *(const short8*)(w1p + (size_t)((kt * 17 + nt) * 64 + lane) * 8);
        int col = nt * 16 + nl;
        bool cok = col < HID_;
        float bias = cok ? b1[col] : 0.f;
#pragma unroll
        for (int mt = 0; mt < 4; ++mt) {
          floatx4 acc = {0.f, 0.f, 0.f, 0.f};
          const unsigned short* ap = A1 + (mt * 16 + nl) * 104 + q4 * 8;
#pragma unroll
          for (int kt = 0; kt < 3; ++kt) {
            short8 a = *(const short8*)(ap + kt * 32);
            acc = __builtin_amdgcn_mfma_f32_16x16x32_bf16(a, bfr[kt], acc, 0, 0, 0);
          }
#pragma unroll
          for (int r = 0; r < 4; ++r) {
            int row = mt * 16 + q4 * 4 + r;
            float g = 0.f;
            if (cok) {
              float v = acc[r] + bias;
              g = gelu_tanh(v);
              H1[row * 296 + col] = f2bf(g);
            }
            float s1 = g, s2 = g * g;
#pragma unroll
            for (int off = 1; off < 16; off <<= 1) {
              s1 += __shfl_xor(s1, off);
              s2 += __shfl_xor(s2, off);
            }
            if (nl == 0) { atomicAdd(&s_sum[row], s1); atomicAdd(&s_sum2[row], s2); }
          }
        }
      }
      __syncthreads();
      if (tid < 64) {
        float mu = s_sum[tid] * (1.f / HID_);
        float var = s_sum2[tid] * (1.f / HID_) - mu * mu;
        s_mu[tid] = mu;
        s_rs[tid] = rsqrtf(var + EPS_);
      }
      __syncthreads();
      // LN1 in place (bf16), zero stats for LN2
      for (int e = tid; e < 64 * HID_; e += 512) {
        int r = e / HID_, cc = e - r * HID_;
        float g = bf2f(H1[r * 296 + cc]);
        float v = (g - s_mu[r]) * s_rs[r] * g1[cc] + be1[cc];
        H1[r * 296 + cc] = f2bf(v);
      }
      if (tid < 64) { s_sum[tid] = 0.f; s_sum2[tid] = 0.f; }
      __syncthreads();

      // GEMM2: (64x288) @ (288x128)
      {
        int nt = wv;
        short8 bfr2[9];
#pragma unroll
        for (int kt = 0; kt < 9; ++kt)
          bfr2[kt] = *(const short8*)(w2p + (size_t)((kt * 8 + nt) * 64 + lane) * 8);
        int col = nt * 16 + nl;
        float bias = b2[col];
#pragma unroll
        for (int mt = 0; mt < 4; ++mt) {
          floatx4 acc = {0.f, 0.f, 0.f, 0.f};
          const unsigned short* ap = H1 + (mt * 16 + nl) * 296 + q4 * 8;
#pragma unroll
          for (int kt = 0; kt < 9; ++kt) {
            short8 a = *(const short8*)(ap + kt * 32);
            acc = __builtin_amdgcn_mfma_f32_16x16x32_bf16(a, bfr2[kt], acc, 0, 0, 0);
          }
#pragma unroll
          for (int r = 0; r < 4; ++r) {
            int row = mt * 16 + q4 * 4 + r;
            float v = acc[r] + bias;
            H2[row * 132 + col] = v;
            float s1 = v, s2 = v * v;
#pragma unroll
            for (int off = 1; off < 16; off <<= 1) {
              s1 += __shfl_xor(s1, off);
              s2 += __shfl_xor(s2, off);
            }
            if (nl == 0) { atomicAdd(&s_sum[row], s1); atomicAdd(&s_sum2[row], s2); }
          }
        }
      }
      __syncthreads();
      if (tid < 64) {
        float mu = s_sum[tid] * (1.f / OUT_);
        float var = s_sum2[tid] * (1.f / OUT_) - mu * mu;
        s_mu[tid] = mu;
        s_rs[tid] = rsqrtf(var + EPS_);
      }
      __syncthreads();
      if (tid < 256) {
        int q = tid >> 7, col = tid & 127;
        float gg = g2[col], bb = be2[col];
        float mx = -3.4e38f;
#pragma unroll 4
        for (int r = 0; r < K_; ++r) {
          int row = q * K_ + r;
          float v = H2[row * 132 + col];
          float o = (v - s_mu[row]) * s_rs[row] * gg + bb;
          mx = fmaxf(mx, o);
        }
        out1[(size_t)(cm0 + q) * OUT_ + col] = mx;   // FLOAT32 output
      }
      __syncthreads();
    }
  }
}

extern "C" void kernel_launch(void* const* d_in, const int* in_sizes, int n_in,
                              void* d_out, int out_size, void* d_ws, size_t ws_size,
                              hipStream_t stream) {
  const float* x = (const float*)d_in[0];
  const float* features = (const float*)d_in[1];
  const int* first_idx = (const int*)d_in[2];
  const float* w1 = (const float*)d_in[3];
  const float* b1 = (const float*)d_in[4];
  const float* g1 = (const float*)d_in[5];
  const float* be1 = (const float*)d_in[6];
  const float* w2 = (const float*)d_in[7];
  const float* b2 = (const float*)d_in[8];
  const float* g2 = (const float*)d_in[9];
  const float* be2 = (const float*)d_in[10];

  // d_out is FLOAT32: centers (8,2048,3) then out (8,2048,128), concatenated.
  float* centers = (float*)d_out;
  float* out1 = (float*)d_out + (size_t)B_ * M_ * 3;

  // ws layout (bytes): prog [0,1024) cacheline-padded (stride 32 ints/batch) |
  //                    w1p [2097152,2149376) | w2p [2149376,2223104)
  int* prog = (int*)d_ws;
  unsigned short* w1p = (unsigned short*)((char*)d_ws + 2097152);
  unsigned short* w2p = (unsigned short*)((char*)d_ws + 2149376);

  pack_kernel<<<dim3(246), dim3(256), 0, stream>>>(w1, w2, w1p, w2p, prog);
  fused_kernel<<<dim3(B_ + CONS_), dim3(512), 0, stream>>>(
      x, features, first_idx, w1p, b1, g1, be1, w2p, b2, g2, be2,
      centers, out1, prog);
}

// Round 7
// 1888.284 us; speedup vs baseline: 1.6268x; 1.4802x over previous
//
#include <hip/hip_runtime.h>
#include <hip/hip_bf16.h>
#include <math.h>

#define B_ 8
#define N_ 8192
#define C_ 64
#define M_ 2048
#define K_ 32
#define OUT_ 128
#define CIN_ 67
#define HID_ 268
#define EPS_ 1e-6f
#define CONS_ 240      // 8 batches x 30 consumers
#define CAPQ_ 512

typedef short short8 __attribute__((ext_vector_type(8)));
typedef float floatx4 __attribute__((ext_vector_type(4)));

__device__ __forceinline__ unsigned short f2bf(float f) {
  unsigned u = __builtin_bit_cast(unsigned, f);
  u += 0x7fffu + ((u >> 16) & 1u);   // RNE (MFMA input casts only)
  return (unsigned short)(u >> 16);
}
__device__ __forceinline__ float bf2f(unsigned short h) {
  return __builtin_bit_cast(float, (unsigned)h << 16);
}

// Reference-matching distance (verified r13, bit-exact).
__device__ __forceinline__ float d2fma(float ax, float ay, float az,
                                       float bx, float by, float bz) {
#pragma clang fp contract(off)
  float dx = ax - bx, dy = ay - by, dz = az - bz;
  return __builtin_fmaf(dz, dz, __builtin_fmaf(dy, dy, dx * dx));
}

__device__ __forceinline__ float gelu_tanh(float v) {
  const float k0 = 0.7978845608028654f;  // sqrt(2/pi)
  const float k1 = 0.044715f;
  float u = k0 * (v + k1 * v * v * v);
  return 0.5f * v * (1.0f + tanhf(u));
}

// Morton spread of a 4-bit value to bit positions 0,3,6,9
__device__ __forceinline__ int msp4(int v) {
  return (v & 1) | ((v & 2) << 2) | ((v & 4) << 4) | ((v & 8) << 6);
}

// One DPP max step on a u64 key (VALU-only; keys are unsigned so the
// bound_ctrl zero-fill is the identity for max).
template <int CTRL>
__device__ __forceinline__ unsigned long long dpp_umax64(unsigned long long k) {
  int lo = (int)(unsigned)k;
  int hi = (int)(unsigned)(k >> 32);
  unsigned slo = (unsigned)__builtin_amdgcn_update_dpp(0, lo, CTRL, 0xF, 0xF, true);
  unsigned shi = (unsigned)__builtin_amdgcn_update_dpp(0, hi, CTRL, 0xF, 0xF, true);
  unsigned long long o = ((unsigned long long)shi << 32) | (unsigned long long)slo;
  return k > o ? k : o;
}

__device__ __forceinline__ unsigned long long wave_dpp_max64(unsigned long long kk) {
  kk = dpp_umax64<0x111>(kk);   // row_shr:1
  kk = dpp_umax64<0x112>(kk);   // row_shr:2
  kk = dpp_umax64<0x114>(kk);   // row_shr:4
  kk = dpp_umax64<0x118>(kk);   // row_shr:8
  kk = dpp_umax64<0x142>(kk);   // row_bcast:15
  kk = dpp_umax64<0x143>(kk);   // row_bcast:31
  return kk;                     // lane63 holds the 64-lane max
}

// ---------------- Pack f32 weights into MFMA B-fragment order (bf16) ------
// Also zeroes the (cacheline-padded) progress flags before fused_kernel.
__global__ __launch_bounds__(256) void pack_kernel(
    const float* __restrict__ w1, const float* __restrict__ w2,
    unsigned short* __restrict__ w1p, unsigned short* __restrict__ w2p,
    int* __restrict__ prog) {
  if (blockIdx.x == 0) prog[threadIdx.x] = 0;   // 256 ints = 8 padded lines
  int e = blockIdx.x * 256 + threadIdx.x;
  if (e < 3 * 17 * 64 * 8) {
    int j = e & 7, lane = (e >> 3) & 63, fi = e >> 9;
    int kt = fi / 17, nt = fi - kt * 17;
    int k = kt * 32 + (lane >> 4) * 8 + j;
    int n = nt * 16 + (lane & 15);
    float v = (k < CIN_ && n < HID_) ? w1[k * HID_ + n] : 0.f;
    w1p[e] = f2bf(v);
  } else {
    int e2 = e - 3 * 17 * 64 * 8;
    if (e2 < 9 * 8 * 64 * 8) {
      int j = e2 & 7, lane = (e2 >> 3) & 63, fi = e2 >> 9;
      int kt = fi >> 3, nt = fi & 7;
      int k = kt * 32 + (lane >> 4) * 8 + j;
      int n = nt * 16 + (lane & 15);
      float v = (k < HID_) ? w2[k * OUT_ + n] : 0.f;
      w2p[e2] = f2bf(v);
    }
  }
}

// ---------------- Fused producer (FPS) + consumer (ballq+MLP) -------------
// Blocks 0..7: FPS (the R4-verified 1940us chain, verbatim): bound-pruned
// updates, single DPP wave max, parity-buffered cross-wave tree, centers
// via LDS chunk ring, release-published every 32.
// Blocks 8..247: consumers, m-major 2-center pairs. Ball-query distances
// are computed ONCE and register-cached across both passes (bit-identical;
// pass 2 is pure ballot+LDS). Polls/center reads are RELAXED agent atomics
// (no buffer_inv per poll; verified R6).
__global__ __launch_bounds__(512) void fused_kernel(
    const float* __restrict__ x, const float* __restrict__ features,
    const int* __restrict__ first_idx,
    const unsigned short* __restrict__ w1p, const float* __restrict__ b1,
    const float* __restrict__ g1, const float* __restrict__ be1,
    const unsigned short* __restrict__ w2p, const float* __restrict__ b2,
    const float* __restrict__ g2, const float* __restrict__ be2,
    float* __restrict__ centers, float* __restrict__ out1,
    int* __restrict__ prog) {
  __shared__ __align__(16) char smem[131456];
  const int tid = threadIdx.x;
  const int lane = tid & 63;
  const int wv = tid >> 6;   // wave 0..7

  if (blockIdx.x < B_) {
    // ======================= FPS producer (R4 verbatim) =======================
    const int b = blockIdx.x;
    const float* xb = x + (size_t)b * N_ * 3;

    float* s_xyz = (float*)smem;                                   // 98304 B
    char* s_mem = smem + 98304;                                    // 32768 B
    unsigned long long* s_wkey = (unsigned long long*)(smem + 131072);  // [2][8]
    int* s_wsum = (int*)(smem + 131200);                           // 8
    float* s_bb = (float*)(smem + 131232);                         // [8][6]

    int* s_hist = (int*)s_mem;                                     // 4096 ints
    unsigned short* s_perm = (unsigned short*)(s_mem + 16384);     // 8192 shorts
    float* s_cbuf = (float*)s_mem;                                 // 6144 floats (after sort)

    // stage coords: 24576 floats = 6144 float4, coalesced, 12 per thread
    {
      const float4* src = (const float4*)xb;
      float4* dst = (float4*)s_xyz;
#pragma unroll
      for (int i = 0; i < 12; ++i) {
        int e = tid + i * 512;
        dst[e] = src[e];
      }
    }
    for (int i = tid; i < 4096; i += 512) s_hist[i] = 0;
    __syncthreads();

    // ---- batch bbox (any enclosing box is correct; used only for binning) ----
    float bx0 = INFINITY, bx1 = -INFINITY, by0 = INFINITY, by1 = -INFINITY,
          bz0 = INFINITY, bz1 = -INFINITY;
#pragma unroll
    for (int i = 0; i < 16; ++i) {
      int p = tid + i * 512;
      float X = s_xyz[p * 3 + 0], Y = s_xyz[p * 3 + 1], Z = s_xyz[p * 3 + 2];
      bx0 = fminf(bx0, X); bx1 = fmaxf(bx1, X);
      by0 = fminf(by0, Y); by1 = fmaxf(by1, Y);
      bz0 = fminf(bz0, Z); bz1 = fmaxf(bz1, Z);
    }
#pragma unroll
    for (int off = 1; off < 64; off <<= 1) {
      bx0 = fminf(bx0, __shfl_xor(bx0, off)); bx1 = fmaxf(bx1, __shfl_xor(bx1, off));
      by0 = fminf(by0, __shfl_xor(by0, off)); by1 = fmaxf(by1, __shfl_xor(by1, off));
      bz0 = fminf(bz0, __shfl_xor(bz0, off)); bz1 = fmaxf(bz1, __shfl_xor(bz1, off));
    }
    if (lane == 0) {
      s_bb[wv * 6 + 0] = bx0; s_bb[wv * 6 + 1] = bx1; s_bb[wv * 6 + 2] = by0;
      s_bb[wv * 6 + 3] = by1; s_bb[wv * 6 + 4] = bz0; s_bb[wv * 6 + 5] = bz1;
    }
    __syncthreads();
#pragma unroll
    for (int w = 0; w < 8; ++w) {
      bx0 = fminf(bx0, s_bb[w * 6 + 0]); bx1 = fmaxf(bx1, s_bb[w * 6 + 1]);
      by0 = fminf(by0, s_bb[w * 6 + 2]); by1 = fmaxf(by1, s_bb[w * 6 + 3]);
      bz0 = fminf(bz0, s_bb[w * 6 + 4]); bz1 = fmaxf(bz1, s_bb[w * 6 + 5]);
    }
    const float kS = 16.0f * (1.0f - 1e-6f);
    float rx = bx1 - bx0, ry = by1 - by0, rz = bz1 - bz0;
    float sxv = rx > 0.f ? kS / rx : 0.f;
    float syv = ry > 0.f ? kS / ry : 0.f;
    float szv = rz > 0.f ? kS / rz : 0.f;

    // ---- histogram (12-bit Morton cells) ----
#pragma unroll
    for (int i = 0; i < 16; ++i) {
      int p = tid + i * 512;
      int qx = (int)((s_xyz[p * 3 + 0] - bx0) * sxv);
      int qy = (int)((s_xyz[p * 3 + 1] - by0) * syv);
      int qz = (int)((s_xyz[p * 3 + 2] - bz0) * szv);
      qx = qx < 0 ? 0 : (qx > 15 ? 15 : qx);
      qy = qy < 0 ? 0 : (qy > 15 ? 15 : qy);
      qz = qz < 0 ? 0 : (qz > 15 ? 15 : qz);
      int c = msp4(qx) | (msp4(qy) << 1) | (msp4(qz) << 2);
      atomicAdd(&s_hist[c], 1);
    }
    __syncthreads();

    // ---- exclusive scan over 4096 bins (thread owns bins [8t,8t+8)) ----
    {
      int h[8], pre[8];
      int acc = 0;
#pragma unroll
      for (int i = 0; i < 8; ++i) { h[i] = s_hist[tid * 8 + i]; pre[i] = acc; acc += h[i]; }
      int incl = acc;
#pragma unroll
      for (int off = 1; off < 64; off <<= 1) {
        int v = __shfl_up(incl, off);
        if (lane >= off) incl += v;
      }
      int texcl = incl - acc;
      if (lane == 63) s_wsum[wv] = incl;
      __syncthreads();
      int woff = 0;
#pragma unroll
      for (int w = 0; w < 8; ++w) woff += (w < wv) ? s_wsum[w] : 0;
#pragma unroll
      for (int i = 0; i < 8; ++i) s_hist[tid * 8 + i] = woff + texcl + pre[i];
    }
    __syncthreads();

    // ---- scatter: s_perm[pos] = original point index ----
#pragma unroll
    for (int i = 0; i < 16; ++i) {
      int p = tid + i * 512;
      int qx = (int)((s_xyz[p * 3 + 0] - bx0) * sxv);
      int qy = (int)((s_xyz[p * 3 + 1] - by0) * syv);
      int qz = (int)((s_xyz[p * 3 + 2] - bz0) * szv);
      qx = qx < 0 ? 0 : (qx > 15 ? 15 : qx);
      qy = qy < 0 ? 0 : (qy > 15 ? 15 : qy);
      qz = qz < 0 ? 0 : (qz > 15 ? 15 : qz);
      int c = msp4(qx) | (msp4(qy) << 1) | (msp4(qz) << 2);
      int pos = atomicAdd(&s_hist[c], 1);
      s_perm[pos] = (unsigned short)p;
    }
    __syncthreads();

    // ---- load 16 sorted slots/thread; build 2 group bboxes (8 pts each) ----
    float px[16], py[16], pz[16], d[16];
    unsigned lo32[16];
    float gx0[2], gx1[2], gy0[2], gy1[2], gz0[2], gz1[2];
#pragma unroll
    for (int g = 0; g < 2; ++g) {
      gx0[g] = INFINITY; gx1[g] = -INFINITY; gy0[g] = INFINITY;
      gy1[g] = -INFINITY; gz0[g] = INFINITY; gz1[g] = -INFINITY;
    }
#pragma unroll
    for (int i = 0; i < 16; ++i) {
      int p = (int)s_perm[tid * 16 + i];
      int g = i >> 3;
      px[i] = s_xyz[p * 3 + 0];
      py[i] = s_xyz[p * 3 + 1];
      pz[i] = s_xyz[p * 3 + 2];
      d[i] = INFINITY;   // fminf(inf, v) == v exactly -> first update installs d0
      lo32[i] = 0xFFFFFFFFu - (unsigned)p;
      gx0[g] = fminf(gx0[g], px[i]); gx1[g] = fmaxf(gx1[g], px[i]);
      gy0[g] = fminf(gy0[g], py[i]); gy1[g] = fmaxf(gy1[g], py[i]);
      gz0[g] = fminf(gz0[g], pz[i]); gz1[g] = fmaxf(gz1[g], pz[i]);
    }

    int fi = first_idx[b];
    float ncx = s_xyz[fi * 3 + 0], ncy = s_xyz[fi * 3 + 1], ncz = s_xyz[fi * 3 + 2];
    if (tid == 0) {   // hist region is dead now; s_cbuf aliases it
      s_cbuf[0] = ncx; s_cbuf[1] = ncy; s_cbuf[2] = ncz;
    }

    unsigned long long gkey[2];
    gkey[0] = 0x7F800000ULL << 32;   // inf max-d, lo=0
    gkey[1] = 0x7F800000ULL << 32;
    unsigned long long wk = 0x7F800000ULL << 32;  // per-lane cached prefix max

    for (int it = 1; it < M_; ++it) {
      // group-level conservative bounds (see R2 notes; __any makes it uniform)
      bool tr[2];
#pragma unroll
      for (int g = 0; g < 2; ++g) {
        float gdx = fmaxf(fmaxf(gx0[g] - ncx, ncx - gx1[g]), 0.f);
        float gdy = fmaxf(fmaxf(gy0[g] - ncy, ncy - gy1[g]), 0.f);
        float gdz = fmaxf(fmaxf(gz0[g] - ncz, ncz - gz1[g]), 0.f);
        float glb = __builtin_fmaf(gdz, gdz, __builtin_fmaf(gdy, gdy, gdx * gdx));
        float ggm = __builtin_bit_cast(float, (unsigned)(gkey[g] >> 32));
        tr[g] = glb * 0.999f < ggm;
      }
      if (__any(tr[0] || tr[1])) {
#pragma unroll
        for (int g = 0; g < 2; ++g) {
          if (tr[g]) {
            unsigned long long k[8];
#pragma unroll
            for (int i = 0; i < 8; ++i) {
              int s = g * 8 + i;
              float dd = d2fma(px[s], py[s], pz[s], ncx, ncy, ncz);
              float dm = fminf(d[s], dd);
              d[s] = dm;
              k[i] = ((unsigned long long)__builtin_bit_cast(unsigned, dm) << 32) |
                     (unsigned long long)lo32[s];
            }
#pragma unroll
            for (int sd = 4; sd >= 1; sd >>= 1)
#pragma unroll
              for (int i = 0; i < sd; ++i)
                k[i] = k[i] > k[i + sd] ? k[i] : k[i + sd];
            gkey[g] = k[0];
          }
        }
        unsigned long long kk = gkey[0] > gkey[1] ? gkey[0] : gkey[1];
        wk = wave_dpp_max64(kk);
      }
      if (lane == 63) s_wkey[(it & 1) * 8 + wv] = wk;
      __syncthreads();
      // publish chunk [it-32, it): centers already in s_cbuf (writes preceded
      // the barrier just crossed). Wave 0 flushes; t0 release-stores prog.
      if ((it & 31) == 0) {
        if (wv == 0 && lane < 24) {
          const float4* src = (const float4*)(s_cbuf + (size_t)(it - 32) * 3);
          float4* dst = (float4*)(centers + (size_t)b * M_ * 3 + (size_t)(it - 32) * 3);
          dst[lane] = src[lane];
        }
        if (tid == 0)
          __hip_atomic_store(&prog[b * 32], it, __ATOMIC_RELEASE, __HIP_MEMORY_SCOPE_AGENT);
      }
      // cross-wave: 4 broadcast ds_read_b128 (parallel latency) + register tree
      {
        const ulonglong2* sp = (const ulonglong2*)(&s_wkey[(it & 1) * 8]);
        ulonglong2 q0 = sp[0], q1 = sp[1], q2 = sp[2], q3 = sp[3];
        unsigned long long a0 = q0.x > q0.y ? q0.x : q0.y;
        unsigned long long a1 = q1.x > q1.y ? q1.x : q1.y;
        unsigned long long a2 = q2.x > q2.y ? q2.x : q2.y;
        unsigned long long a3 = q3.x > q3.y ? q3.x : q3.y;
        unsigned long long b0 = a0 > a1 ? a0 : a1;
        unsigned long long b1v = a2 > a3 ? a2 : a3;
        unsigned long long gk = b0 > b1v ? b0 : b1v;
        int gi = (int)(0xFFFFFFFFu - (unsigned)(gk & 0xFFFFFFFFull));
        int gs = __builtin_amdgcn_readfirstlane(gi);   // uniform index
        ncx = s_xyz[gs * 3 + 0];                        // LDS broadcast fetch
        ncy = s_xyz[gs * 3 + 1];
        ncz = s_xyz[gs * 3 + 2];
      }
      if (tid == 0) {
        s_cbuf[it * 3 + 0] = ncx; s_cbuf[it * 3 + 1] = ncy; s_cbuf[it * 3 + 2] = ncz;
      }
      // no second barrier: next iteration writes the other parity buffer
    }

    // final chunk (centers 2016..2047) + completion publish
    __syncthreads();
    if (wv == 0 && lane < 24) {
      const float4* src = (const float4*)(s_cbuf + (size_t)(M_ - 32) * 3);
      float4* dst = (float4*)(centers + (size_t)b * M_ * 3 + (size_t)(M_ - 32) * 3);
      dst[lane] = src[lane];
    }
    if (tid == 0)
      __hip_atomic_store(&prog[b * 32], M_, __ATOMIC_RELEASE, __HIP_MEMORY_SCOPE_AGENT);

  } else {
    // ================ consumer: 2-center ballq + 64-row MLP ================
    unsigned short* A1 = (unsigned short*)smem;            // [64][104] bf16
    unsigned short* H1 = (unsigned short*)(smem + 13312);  // [64][296] bf16
    float* H2 = (float*)(smem + 51200);                    // [64][132] f32
    float* cd = (float*)(smem + 84992);                    // [2][512]
    int* cidx = (int*)(smem + 89088);                      // [2][512]
    float* s_sum = (float*)(smem + 93184);                 // [64]
    float* s_sum2 = (float*)(smem + 93440);                // [64]
    float* s_mu = (float*)(smem + 93696);                  // [64]
    float* s_rs = (float*)(smem + 93952);                  // [64]
    int* s_nbr = (int*)(smem + 94208);                     // [64]
    float* s_ctr = (float*)(smem + 94464);                 // [6]
    int* s_wc = (int*)(smem + 94496);                      // [2][8]

    const int j = (int)blockIdx.x - B_;     // 0..239
    const int b = j & 7;                    // owned batch
    const int c = j >> 3;                   // 0..29 within batch
    const int q4 = lane >> 4;  // quad 0..3
    const int nl = lane & 15;

    for (int e = tid; e < 64 * 104; e += 512) A1[e] = 0;
    for (int e = tid; e < 64 * 296; e += 512) H1[e] = 0;
    __syncthreads();

    const float* xb = x + (size_t)b * N_ * 3;

    for (int k35 = 0; k35 < 35; ++k35) {
      int i = c + 30 * k35;                 // pair index, block-uniform
      if (i >= 1024) break;
      const int m0 = 2 * i, m1 = m0 + 1;
      const int cm0 = b * M_ + m0;

      // RELAXED agent polls: coherence-point reads, NO cache invalidation.
      if (tid == 0) {
        while (__hip_atomic_load(&prog[b * 32], __ATOMIC_RELAXED,
                                 __HIP_MEMORY_SCOPE_AGENT) <= m1)
          __builtin_amdgcn_s_sleep(32);
      }
      __syncthreads();

      if (tid < 64) s_sum[tid] = 0.f;
      else if (tid < 128) s_sum2[tid - 64] = 0.f;
      else if (tid < 134) {
        // bypassing reads of the 6 center words (producer release-flushed
        // them to the coherence point before bumping prog)
        unsigned wrd = __hip_atomic_load(
            (const unsigned*)&centers[(size_t)cm0 * 3 + (tid - 128)],
            __ATOMIC_RELAXED, __HIP_MEMORY_SCOPE_AGENT);
        s_ctr[tid - 128] = __builtin_bit_cast(float, wrd);
      }
      __syncthreads();

      const float c0x = s_ctr[0], c0y = s_ctr[1], c0z = s_ctr[2];
      const float c1x = s_ctr[3], c1y = s_ctr[4], c1z = s_ctr[5];

      // ---- ball query, both centers, ONE x-scan; distances register-cached
      float d20c[16], d21c[16];
      int cnt0 = 0, cnt1 = 0;
#pragma unroll
      for (int s = 0; s < 16; ++s) {
        int p = wv * 1024 + s * 64 + lane;
        float X = xb[p * 3 + 0], Y = xb[p * 3 + 1], Z = xb[p * 3 + 2];
        d20c[s] = d2fma(X, Y, Z, c0x, c0y, c0z);
        d21c[s] = d2fma(X, Y, Z, c1x, c1y, c1z);
        cnt0 += (int)__popcll(__ballot(d20c[s] < 0.09f));
        cnt1 += (int)__popcll(__ballot(d21c[s] < 0.09f));
      }
      if (lane == 0) { s_wc[wv] = cnt0; s_wc[8 + wv] = cnt1; }
      __syncthreads();
      int base0 = 0, tot0 = 0, base1 = 0, tot1 = 0;
#pragma unroll
      for (int w = 0; w < 8; ++w) {
        int v0 = s_wc[w], v1 = s_wc[8 + w];
        base0 += (w < wv) ? v0 : 0; tot0 += v0;
        base1 += (w < wv) ? v1 : 0; tot1 += v1;
      }
      int count0 = tot0 < CAPQ_ ? tot0 : CAPQ_;
      int count1 = tot1 < CAPQ_ ? tot1 : CAPQ_;
      // pass 2: pure ballot+LDS writes from cached distances (bit-identical)
      int pos0 = base0, pos1 = base1;
#pragma unroll
      for (int s = 0; s < 16; ++s) {
        int p = wv * 1024 + s * 64 + lane;
        float d20 = d20c[s], d21 = d21c[s];
        bool in0 = d20 < 0.09f;   // f32(0.3**2), strict <
        bool in1 = d21 < 0.09f;
        unsigned long long m0m = __ballot(in0);
        unsigned long long m1m = __ballot(in1);
        if (in0) {
          int pp = pos0 + (int)__popcll(m0m & ((1ull << lane) - 1ull));
          if (pp < CAPQ_) { cd[pp] = d20; cidx[pp] = p; }
        }
        if (in1) {
          int pp = pos1 + (int)__popcll(m1m & ((1ull << lane) - 1ull));
          if (pp < CAPQ_) { cd[CAPQ_ + pp] = d21; cidx[CAPQ_ + pp] = p; }
        }
        pos0 += (int)__popcll(m0m);
        pos1 += (int)__popcll(m1m);
      }
      __syncthreads();
      // rank-select K nearest per center (stable order), 256 threads each
      {
        int q = tid >> 8;                  // 0 or 1
        int lt = tid & 255;
        int cnt = q ? count1 : count0;
        int nw = cnt < K_ ? cnt : K_;
        const float* cdq = cd + q * CAPQ_;
        const int* cxq = cidx + q * CAPQ_;
        for (int cc = lt; cc < cnt; cc += 256) {
          float dcc = cdq[cc];
          int rank = 0;
          for (int jj = 0; jj < cnt; ++jj) {
            float dj = cdq[jj];
            rank += (dj < dcc || (dj == dcc && jj < cc)) ? 1 : 0;  // stable
          }
          if (rank < K_) s_nbr[q * K_ + rank] = cxq[cc];
        }
        for (int s = nw + lt; s < K_; s += 256) s_nbr[q * K_ + s] = N_ - 1;
      }
      __syncthreads();

      // ---- gather: 16 threads per neighbor row, 64 rows in 2 halves
#pragma unroll
      for (int hh = 0; hh < 2; ++hh) {
        int rr = (tid >> 4) + hh * 32;     // row 0..63
        int jj = tid & 15;
        int q = rr >> 5;
        int idx = s_nbr[rr];
        const float4* frow = (const float4*)(features + ((size_t)b * N_ + idx) * C_);
        float4 f4 = frow[jj];
        int base = rr * 104 + jj * 4;
        A1[base + 0] = f2bf(f4.x); A1[base + 1] = f2bf(f4.y);
        A1[base + 2] = f2bf(f4.z); A1[base + 3] = f2bf(f4.w);
        if (jj == 0) {
          const float* xp = x + ((size_t)b * N_ + idx) * 3;
          A1[rr * 104 + 64] = f2bf(xp[0] - s_ctr[q * 3 + 0]);
          A1[rr * 104 + 65] = f2bf(xp[1] - s_ctr[q * 3 + 1]);
          A1[rr * 104 + 66] = f2bf(xp[2] - s_ctr[q * 3 + 2]);
        }
      }
      __syncthreads();

      // GEMM1: (64x96) @ (96x272)
      for (int nt = wv; nt < 17; nt += 8) {
        short8 bfr[3];
#pragma unroll
        for (int kt = 0; kt < 3; ++kt)
          bfr[kt] = *(const short8*)(w1p + (size_t)((kt * 17 + nt) * 64 + lane) * 8);
        int col = nt * 16 + nl;
        bool cok = col < HID_;
        float bias = cok ? b1[col] : 0.f;
#pragma unroll
        for (int mt = 0; mt < 4; ++mt) {
          floatx4 acc = {0.f, 0.f, 0.f, 0.f};
          const unsigned short* ap = A1 + (mt * 16 + nl) * 104 + q4 * 8;
#pragma unroll
          for (int kt = 0; kt < 3; ++kt) {
            short8 a = *(const short8*)(ap + kt * 32);
            acc = __builtin_amdgcn_mfma_f32_16x16x32_bf16(a, bfr[kt], acc, 0, 0, 0);
          }
#pragma unroll
          for (int r = 0; r < 4; ++r) {
            int row = mt * 16 + q4 * 4 + r;
            float g = 0.f;
            if (cok) {
              float v = acc[r] + bias;
              g = gelu_tanh(v);
              H1[row * 296 + col] = f2bf(g);
            }
            float s1 = g, s2 = g * g;
#pragma unroll
            for (int off = 1; off < 16; off <<= 1) {
              s1 += __shfl_xor(s1, off);
              s2 += __shfl_xor(s2, off);
            }
            if (nl == 0) { atomicAdd(&s_sum[row], s1); atomicAdd(&s_sum2[row], s2); }
          }
        }
      }
      __syncthreads();
      if (tid < 64) {
        float mu = s_sum[tid] * (1.f / HID_);
        float var = s_sum2[tid] * (1.f / HID_) - mu * mu;
        s_mu[tid] = mu;
        s_rs[tid] = rsqrtf(var + EPS_);
      }
      __syncthreads();
      // LN1 in place (bf16), zero stats for LN2
      for (int e = tid; e < 64 * HID_; e += 512) {
        int r = e / HID_, cc = e - r * HID_;
        float g = bf2f(H1[r * 296 + cc]);
        float v = (g - s_mu[r]) * s_rs[r] * g1[cc] + be1[cc];
        H1[r * 296 + cc] = f2bf(v);
      }
      if (tid < 64) { s_sum[tid] = 0.f; s_sum2[tid] = 0.f; }
      __syncthreads();

      // GEMM2: (64x288) @ (288x128)
      {
        int nt = wv;
        short8 bfr2[9];
#pragma unroll
        for (int kt = 0; kt < 9; ++kt)
          bfr2[kt] = *(const short8*)(w2p + (size_t)((kt * 8 + nt) * 64 + lane) * 8);
        int col = nt * 16 + nl;
        float bias = b2[col];
#pragma unroll
        for (int mt = 0; mt < 4; ++mt) {
          floatx4 acc = {0.f, 0.f, 0.f, 0.f};
          const unsigned short* ap = H1 + (mt * 16 + nl) * 296 + q4 * 8;
#pragma unroll
          for (int kt = 0; kt < 9; ++kt) {
            short8 a = *(const short8*)(ap + kt * 32);
            acc = __builtin_amdgcn_mfma_f32_16x16x32_bf16(a, bfr2[kt], acc, 0, 0, 0);
          }
#pragma unroll
          for (int r = 0; r < 4; ++r) {
            int row = mt * 16 + q4 * 4 + r;
            float v = acc[r] + bias;
            H2[row * 132 + col] = v;
            float s1 = v, s2 = v * v;
#pragma unroll
            for (int off = 1; off < 16; off <<= 1) {
              s1 += __shfl_xor(s1, off);
              s2 += __shfl_xor(s2, off);
            }
            if (nl == 0) { atomicAdd(&s_sum[row], s1); atomicAdd(&s_sum2[row], s2); }
          }
        }
      }
      __syncthreads();
      if (tid < 64) {
        float mu = s_sum[tid] * (1.f / OUT_);
        float var = s_sum2[tid] * (1.f / OUT_) - mu * mu;
        s_mu[tid] = mu;
        s_rs[tid] = rsqrtf(var + EPS_);
      }
      __syncthreads();
      if (tid < 256) {
        int q = tid >> 7, col = tid & 127;
        float gg = g2[col], bb = be2[col];
        float mx = -3.4e38f;
#pragma unroll 4
        for (int r = 0; r < K_; ++r) {
          int row = q * K_ + r;
          float v = H2[row * 132 + col];
          float o = (v - s_mu[row]) * s_rs[row] * gg + bb;
          mx = fmaxf(mx, o);
        }
        out1[(size_t)(cm0 + q) * OUT_ + col] = mx;   // FLOAT32 output
      }
      __syncthreads();
    }
  }
}

extern "C" void kernel_launch(void* const* d_in, const int* in_sizes, int n_in,
                              void* d_out, int out_size, void* d_ws, size_t ws_size,
                              hipStream_t stream) {
  const float* x = (const float*)d_in[0];
  const float* features = (const float*)d_in[1];
  const int* first_idx = (const int*)d_in[2];
  const float* w1 = (const float*)d_in[3];
  const float* b1 = (const float*)d_in[4];
  const float* g1 = (const float*)d_in[5];
  const float* be1 = (const float*)d_in[6];
  const float* w2 = (const float*)d_in[7];
  const float* b2 = (const float*)d_in[8];
  const float* g2 = (const float*)d_in[9];
  const float* be2 = (const float*)d_in[10];

  // d_out is FLOAT32: centers (8,2048,3) then out (8,2048,128), concatenated.
  float* centers = (float*)d_out;
  float* out1 = (float*)d_out + (size_t)B_ * M_ * 3;

  // ws layout (bytes): prog [0,1024) cacheline-padded (stride 32 ints/batch) |
  //                    w1p [2097152,2149376) | w2p [2149376,2223104)
  int* prog = (int*)d_ws;
  unsigned short* w1p = (unsigned short*)((char*)d_ws + 2097152);
  unsigned short* w2p = (unsigned short*)((char*)d_ws + 2149376);

  pack_kernel<<<dim3(246), dim3(256), 0, stream>>>(w1, w2, w1p, w2p, prog);
  fused_kernel<<<dim3(B_ + CONS_), dim3(512), 0, stream>>>(
      x, features, first_idx, w1p, b1, g1, be1, w2p, b2, g2, be2,
      centers, out1, prog);
}